// Round 7
// baseline (282.049 us; speedup 1.0000x reference)
//
#include <hip/hip_runtime.h>
#include <hip/hip_bf16.h>

#define BB   4
#define CC   128
#define HH   192
#define WWd  192
#define HWp  (HH*WWd)      // 36864
#define OO   128
#define KK   7
#define NPIX (BB*HWp)      // 147456
#define TILE 64

typedef short bf16x8 __attribute__((ext_vector_type(8)));
typedef float f32x4  __attribute__((ext_vector_type(4)));

static __device__ __forceinline__ unsigned f2bf(float f) {
    union { __hip_bfloat16 h; unsigned short u; } cvt;
    cvt.h = __float2bfloat16(f);
    return (unsigned)cvt.u;
}

static __device__ __forceinline__ void gload_lds16(const float* g, void* lds) {
    __builtin_amdgcn_global_load_lds(
        (const __attribute__((address_space(1))) void*)g,
        (__attribute__((address_space(3))) void*)lds, 16, 0, 0);
}

// ---- prep: Wsum[o][c] = sum_k kernel_w[o*7+k, c] -> bf16 in MFMA A-frag order;
//      bsum[o] = sum_k kernel_b[o*7+k] (fp32).  (validated rounds 1/5/6)
__global__ __launch_bounds__(256) void prep_kernel(const float* __restrict__ kw,
                                                   const float* __restrict__ kb,
                                                   unsigned short* __restrict__ wfrag,
                                                   float* __restrict__ bsum) {
    int tid = blockIdx.x * 256 + threadIdx.x;   // 0..16383
    int o = tid >> 7, c = tid & 127;
    float s = 0.f;
#pragma unroll
    for (int k = 0; k < KK; ++k) s += kw[(o*KK + k)*CC + c];
    // conv reads: afrag[mt][ks] of wave w lane l elem j <-> o = w*32+mt*16+(l&15), c = ks*32+(l>>4)*8+j
    int wv = o >> 5, mt = (o >> 4) & 1, lo = o & 15;
    int ks = c >> 5, g = (c >> 3) & 3, j = c & 7;
    int idx = ((((wv*2 + mt)*4 + ks)*64) + (lo + 16*g))*8 + j;
    wfrag[idx] = (unsigned short)f2bf(s);
    if (c == 0) {
        float bs = 0.f;
#pragma unroll
        for (int k = 0; k < KK; ++k) bs += kb[o*KK + k];
        bsum[o] = bs;
    }
}

// ---- main: 256 threads = 4 waves; block = 64 pixels x 128 outputs; wave = 32 outputs.
// Stage A: pure DMA (global_load_lds x16B), fp32 [c][64pix] rows, XOR-swizzled source
// quads (rule #21: swizzle both sides). One barrier. Stage C: 8x ds_read_b32 + cvt per
// B-frag (2-way banks = free); channel sums ride the same fp32 reads (no sPart LDS).
__global__ __launch_bounds__(256) void conv_kernel(const float* __restrict__ x,
                                                   const unsigned short* __restrict__ wfrag,
                                                   const float* __restrict__ bsum,
                                                   float* __restrict__ out) {
    __shared__ __align__(16) float xc[CC][TILE];   // 32 KB, 256-B rows

    const int t = threadIdx.x;
    const int w = t >> 6;            // wave 0..3: outputs [w*32, w*32+32); stages channels [w*32, +32)
    const int l = t & 63;
    const int lo16 = l & 15, g4 = l >> 4;

    const int pixBase = blockIdx.x * TILE;
    const int bIdx   = pixBase / HWp;
    const int hwBase = pixBase - bIdx * HWp;     // multiple of 64
    const float* xb  = x + (size_t)bIdx * CC * HWp + hwBase;

    // ---- Stage A: 8 DMA instrs per wave; lane l -> row c0+(l>>4), source quad (l&15)^ (swz<<2)
#pragma unroll
    for (int it = 0; it < 8; ++it) {
        const int c0  = w*32 + it*4;
        const int swz = (c0 >> 3) & 1;                       // constant over the 4 rows (c0%4==0)
        const int row = c0 + (l >> 4);
        const int qd  = (l & 15) ^ (swz << 2);               // pixel-quad, bit2 = pixel bit4
        gload_lds16(xb + (size_t)row * HWp + qd * 4, &xc[c0][0]);
    }

    // A-fragments hoisted (wfrag L2-resident): 2 m-tiles x 4 k-steps = 32 VGPR
    bf16x8 afrag[2][4];
    const unsigned short* wf = wfrag + (size_t)w * 2*4*64*8;
#pragma unroll
    for (int mt = 0; mt < 2; ++mt)
#pragma unroll
        for (int ks = 0; ks < 4; ++ks)
            afrag[mt][ks] = *reinterpret_cast<const bf16x8*>(wf + ((size_t)(mt*4 + ks)*64 + l)*8);

    __syncthreads();   // drains DMA (vmcnt 0) + barrier

    // ---- Stage C: D[o][pix] = A(Wsum) x B(x); B-frag = 8 ch-strided fp32 LDS reads -> bf16
    f32x4 acc[2][4];
#pragma unroll
    for (int mt = 0; mt < 2; ++mt)
#pragma unroll
        for (int nt = 0; nt < 4; ++nt)
            acc[mt][nt] = (f32x4){0.f, 0.f, 0.f, 0.f};
    float csum[4] = {0.f, 0.f, 0.f, 0.f};
    const int swzr = (g4 & 1) << 4;                          // read-side pixel swizzle

#pragma unroll 1
    for (int ks = 0; ks < 4; ++ks) {
        const int crow = ks*32 + g4*8;                       // 8 contiguous channels for this lane
#pragma unroll
        for (int nt = 0; nt < 4; ++nt) {
            const float* base = &xc[crow][(nt*16 + lo16) ^ swzr];
            float v[8];
#pragma unroll
            for (int j = 0; j < 8; ++j) v[j] = base[j * TILE];
            bf16x8 b;
            float cs = 0.f;
#pragma unroll
            for (int j = 0; j < 8; ++j) { cs += v[j]; b[j] = (short)f2bf(v[j]); }
            csum[nt] += cs;
            acc[0][nt] = __builtin_amdgcn_mfma_f32_16x16x32_bf16(afrag[0][ks], b, acc[0][nt], 0, 0, 0);
            acc[1][nt] = __builtin_amdgcn_mfma_f32_16x16x32_bf16(afrag[1][ks], b, acc[1][nt], 0, 0, 0);
        }
    }
    // full 128-channel sum for pixel nt*16+lo16 (reduce the 4 g4 channel-slices)
#pragma unroll
    for (int nt = 0; nt < 4; ++nt) {
        csum[nt] += __shfl_xor(csum[nt], 16);
        csum[nt] += __shfl_xor(csum[nt], 32);
    }

    // ---- Epilogue: out[o,p] = s[p] * (dot + bsum[o]); D row = g4*4+r, col = lo16 (+16nt)
    float* ob = out + (size_t)bIdx * OO * HWp + hwBase + lo16;
#pragma unroll
    for (int nt = 0; nt < 4; ++nt) {
        const float sv = csum[nt];
#pragma unroll
        for (int mt = 0; mt < 2; ++mt) {
            const int o0 = w*32 + mt*16 + g4*4;
            const float4 bs4 = *reinterpret_cast<const float4*>(bsum + o0);
#pragma unroll
            for (int r = 0; r < 4; ++r) {
                const float bsv = (r == 0) ? bs4.x : (r == 1) ? bs4.y : (r == 2) ? bs4.z : bs4.w;
                ob[(size_t)(o0 + r) * HWp + nt*16] = (acc[mt][nt][r] + bsv) * sv;
            }
        }
    }
}

extern "C" void kernel_launch(void* const* d_in, const int* in_sizes, int n_in,
                              void* d_out, int out_size, void* d_ws, size_t ws_size,
                              hipStream_t stream) {
    const float* x  = (const float*)d_in[0];
    // d_in[1] offsets, d_in[2] tumor_center: mathematically dead (grid_sample on 1x1 input)
    const float* kw = (const float*)d_in[3];
    const float* kb = (const float*)d_in[4];
    float* outp = (float*)d_out;

    unsigned short* wfrag = (unsigned short*)d_ws;                 // 128*128 bf16 = 32 KB
    float* bsum = (float*)((char*)d_ws + 32768);                   // 128 f32

    prep_kernel<<<dim3(64), dim3(256), 0, stream>>>(kw, kb, wfrag, bsum);
    conv_kernel<<<dim3(NPIX / TILE), dim3(256), 0, stream>>>(x, wfrag, bsum, outp);
}

// Round 8
// 35.233 us; speedup vs baseline: 8.0052x; 8.0052x over previous
//
#include <hip/hip_runtime.h>
#include <hip/hip_bf16.h>

#define BB   4
#define CC   128
#define HH   192
#define WWd  192
#define HWp  (HH*WWd)      // 36864
#define OO   128
#define KK   7
#define NPIX (BB*HWp)      // 147456
#define TILE 64
#define GRIDB 768          // 3 blocks/CU exactly
#define NT   3             // 768 * 3 * 64 = 147456 pixels
#define XT_PITCH_B 272     // bytes per pixel row (136 shorts; b128-read validated R1/R5/R6)

typedef short bf16x8 __attribute__((ext_vector_type(8)));
typedef float f32x4  __attribute__((ext_vector_type(4)));

static __device__ __forceinline__ unsigned f2bf(float f) {
    union { __hip_bfloat16 h; unsigned short u; } cvt;
    cvt.h = __float2bfloat16(f);
    return (unsigned)cvt.u;
}

// ---- prep: Wsum[o][c] = sum_k kernel_w[o*7+k, c] -> bf16 in MFMA A-frag order;
//      bsum[o] = sum_k kernel_b[o*7+k] (fp32).  (validated rounds 1/5/6)
__global__ __launch_bounds__(256) void prep_kernel(const float* __restrict__ kw,
                                                   const float* __restrict__ kb,
                                                   unsigned short* __restrict__ wfrag,
                                                   float* __restrict__ bsum) {
    int tid = blockIdx.x * 256 + threadIdx.x;   // 0..16383
    int o = tid >> 7, c = tid & 127;
    float s = 0.f;
#pragma unroll
    for (int k = 0; k < KK; ++k) s += kw[(o*KK + k)*CC + c];
    // conv reads: afrag[mt][ks] of wave w lane l elem j <-> o = w*32+mt*16+(l&15), c = ks*32+(l>>4)*8+j
    int wv = o >> 5, mt = (o >> 4) & 1, lo = o & 15;
    int ks = c >> 5, g = (c >> 3) & 3, j = c & 7;
    int idx = ((((wv*2 + mt)*4 + ks)*64) + (lo + 16*g))*8 + j;
    wfrag[idx] = (unsigned short)f2bf(s);
    if (c == 0) {
        float bs = 0.f;
#pragma unroll
        for (int k = 0; k < KK; ++k) bs += kb[o*KK + k];
        bsum[o] = bs;
    }
}

// ---- main: persistent, 3 tiles/block. Per tile: prefetch next tile's 32 dwords into
// regs (issue-early), MFMA + epilogue of current tile hides the HBM latency, raw
// s_barrier (reads already consumed -> no drain), pack+ds_write next tile, syncthreads.
__global__ __launch_bounds__(256) void conv_kernel(const float* __restrict__ x,
                                                   const unsigned short* __restrict__ wfrag,
                                                   const float* __restrict__ bsum,
                                                   float* __restrict__ out) {
    __shared__ __align__(16) unsigned char xTb[TILE * XT_PITCH_B];  // 17408 B
    __shared__ float sPart[4][TILE];                                 // 1 KB

    const int t = threadIdx.x;
    const int w = t >> 6;            // wave 0..3: outputs [w*32,+32); stages channels [w*32,+32)
    const int l = t & 63;
    const int lo16 = l & 15, g4 = l >> 4;

    // A-fragments hoisted (wfrag L2-resident): 2 m-tiles x 4 k-steps = 32 VGPR
    bf16x8 afrag[2][4];
    const unsigned short* wf = wfrag + (size_t)w * 2*4*64*8;
#pragma unroll
    for (int mt = 0; mt < 2; ++mt)
#pragma unroll
        for (int ks = 0; ks < 4; ++ks)
            afrag[mt][ks] = *reinterpret_cast<const bf16x8*>(wf + ((size_t)(mt*4 + ks)*64 + l)*8);

    float v[32];

    // ---- prologue: stage tile tau = blockIdx.x
    int tau = blockIdx.x;
    {
        const int pix = tau * TILE;
        const int bi  = pix / HWp;
        const int hw  = pix - bi * HWp;
        const float* xk = x + (size_t)bi * CC * HWp + hw + l;
#pragma unroll
        for (int i = 0; i < 8; ++i)
#pragma unroll
            for (int j = 0; j < 4; ++j)
                v[i*4 + j] = xk[(size_t)(w*32 + i*4 + j) * HWp];
        float cs = 0.f;
#pragma unroll
        for (int i = 0; i < 32; ++i) cs += v[i];
        sPart[w][l] = cs;
#pragma unroll
        for (int i = 0; i < 8; ++i) {
            uint2 u;
            u.x = f2bf(v[i*4+0]) | (f2bf(v[i*4+1]) << 16);
            u.y = f2bf(v[i*4+2]) | (f2bf(v[i*4+3]) << 16);
            *reinterpret_cast<uint2*>(&xTb[l*XT_PITCH_B + (w*32 + i*4)*2]) = u;
        }
        __syncthreads();
    }

    for (int k = 0; k < NT; ++k) {
        const bool more = (k + 1 < NT);

        // ---- prefetch next tile into regs (issued before compute; first use is pack)
        if (more) {
            const int pix = (tau + GRIDB) * TILE;
            const int bi  = pix / HWp;
            const int hw  = pix - bi * HWp;
            const float* xk = x + (size_t)bi * CC * HWp + hw + l;
#pragma unroll
            for (int i = 0; i < 8; ++i)
#pragma unroll
                for (int j = 0; j < 4; ++j)
                    v[i*4 + j] = xk[(size_t)(w*32 + i*4 + j) * HWp];
        }

        // ---- MFMA on current tile (validated R6 path)
        f32x4 acc[2][4];
#pragma unroll
        for (int mt = 0; mt < 2; ++mt)
#pragma unroll
            for (int nt = 0; nt < 4; ++nt)
                acc[mt][nt] = (f32x4){0.f, 0.f, 0.f, 0.f};
#pragma unroll
        for (int ks = 0; ks < 4; ++ks) {
            bf16x8 bfr[4];
#pragma unroll
            for (int nt = 0; nt < 4; ++nt)
                bfr[nt] = *reinterpret_cast<const bf16x8*>(
                    &xTb[(nt*16 + lo16)*XT_PITCH_B + ks*64 + g4*16]);
#pragma unroll
            for (int nt = 0; nt < 4; ++nt) {
                acc[0][nt] = __builtin_amdgcn_mfma_f32_16x16x32_bf16(afrag[0][ks], bfr[nt], acc[0][nt], 0, 0, 0);
                acc[1][nt] = __builtin_amdgcn_mfma_f32_16x16x32_bf16(afrag[1][ks], bfr[nt], acc[1][nt], 0, 0, 0);
            }
        }

        // ---- epilogue for current tile: out[o,p] = s[p] * (dot + bsum[o])
        {
            const int pix = tau * TILE;
            const int bi  = pix / HWp;
            const int hw  = pix - bi * HWp;
            float* ob = out + (size_t)bi * OO * HWp + hw + lo16;
#pragma unroll
            for (int nt = 0; nt < 4; ++nt) {
                const int pp = nt*16 + lo16;
                const float sv = sPart[0][pp] + sPart[1][pp] + sPart[2][pp] + sPart[3][pp];
#pragma unroll
                for (int mt = 0; mt < 2; ++mt) {
                    const int o0 = w*32 + mt*16 + g4*4;
                    const float4 bs4 = *reinterpret_cast<const float4*>(bsum + o0);
#pragma unroll
                    for (int r = 0; r < 4; ++r) {
                        const float bsv = (r == 0) ? bs4.x : (r == 1) ? bs4.y : (r == 2) ? bs4.z : bs4.w;
                        ob[(size_t)(o0 + r) * HWp + nt*16] = (acc[mt][nt][r] + bsv) * sv;
                    }
                }
            }
        }

        // ---- rotate: overwrite LDS with prefetched tile
        if (more) {
            // raw barrier: every thread's xT/sPart reads were consumed by MFMA/FMA data
            // deps before this point, so no vmcnt/lgkm drain needed (avoids m97 stall).
            __builtin_amdgcn_s_barrier();
            float cs = 0.f;
#pragma unroll
            for (int i = 0; i < 32; ++i) cs += v[i];
            sPart[w][l] = cs;
#pragma unroll
            for (int i = 0; i < 8; ++i) {
                uint2 u;
                u.x = f2bf(v[i*4+0]) | (f2bf(v[i*4+1]) << 16);
                u.y = f2bf(v[i*4+2]) | (f2bf(v[i*4+3]) << 16);
                *reinterpret_cast<uint2*>(&xTb[l*XT_PITCH_B + (w*32 + i*4)*2]) = u;
            }
            __syncthreads();
        }
        tau += GRIDB;
    }
}

extern "C" void kernel_launch(void* const* d_in, const int* in_sizes, int n_in,
                              void* d_out, int out_size, void* d_ws, size_t ws_size,
                              hipStream_t stream) {
    const float* x  = (const float*)d_in[0];
    // d_in[1] offsets, d_in[2] tumor_center: mathematically dead (grid_sample on 1x1 input)
    const float* kw = (const float*)d_in[3];
    const float* kb = (const float*)d_in[4];
    float* outp = (float*)d_out;

    unsigned short* wfrag = (unsigned short*)d_ws;                 // 128*128 bf16 = 32 KB
    float* bsum = (float*)((char*)d_ws + 32768);                   // 128 f32

    prep_kernel<<<dim3(64), dim3(256), 0, stream>>>(kw, kb, wfrag, bsum);
    conv_kernel<<<dim3(GRIDB), dim3(256), 0, stream>>>(x, wfrag, bsum, outp);
}